// Round 11
// baseline (5217.794 us; speedup 1.0000x reference)
//
#include <hip/hip_runtime.h>

// LSTM BS=512, T=2048, IN=64, HS=128.
// One dispatch, 256 blocks x 512 thr:
//   blocks 0..127   (scan): 4 batch rows each. Per step: 16 MFMA/wave
//     (K=128 U*h), acc C-init from global Z (2-step reg prefetch), gate
//     redistribution via 2x ds_swizzle(xor16) + 1x ds_bpermute (cross-32)
//     per gate -> 1 cell update per lane (all 64 lanes dense).
//   blocks 128..255 (producer): Z = x@W + bias, one block per group,
//     walking its 64 chunks; written to a 12-chunk ring in d_ws (192 MiB,
//     Infinity-Cache resident), published via agent-scope release flags;
//     consumers publish done[g] so the ring never overwrites live data.
// All 256 blocks co-resident (1/CU) -> producer/consumer spin is safe.

#define T_STEPS 2048
#define IN_DIM 64
#define HS 128
#define NG 512
#define NTHR 512
#define HSTR 136
#define CHK 32
#define NCHK 64
#define GROUPS 128
#define RPG 4
#define PRODS 128
#define NUNITS (NCHK * GROUPS)
#define RING 12

typedef float f32x4 __attribute__((ext_vector_type(4)));
typedef short s16x8 __attribute__((ext_vector_type(8)));

__device__ __forceinline__ unsigned short f2bf(float f) {
  unsigned u = __float_as_uint(f);
  return (unsigned short)((u + 0x7fffu + ((u >> 16) & 1u)) >> 16);  // RNE
}
__device__ __forceinline__ float bf2f(unsigned short s) {
  return __int_as_float(((int)s) << 16);
}
__device__ __forceinline__ float rcpf(float x) { return __builtin_amdgcn_rcpf(x); }
__device__ __forceinline__ float sigm(float x) { return rcpf(1.0f + __expf(-x)); }
__device__ __forceinline__ float tanhfast(float x) {
  return 1.0f - 2.0f * rcpf(__expf(2.0f * x) + 1.0f);  // exact at +-inf
}

__device__ __forceinline__ void wait_ge(int* f, int v) {
  int tries = 0;
  while (__hip_atomic_load(f, __ATOMIC_ACQUIRE, __HIP_MEMORY_SCOPE_AGENT) < v) {
    __builtin_amdgcn_s_sleep(16);
    if (++tries > (1 << 23)) break;   // safety bound; never hit in practice
  }
}

// Z slot for (t-slot, g): 128 cells of 16 shorts; cell (w*16+lrow)
// shorts[r*4+n] = gate n, batch row g*4+r, col n*128+w*16+lrow, bias incl.
__global__ __launch_bounds__(NTHR, 1)
void lstm_mega(const float* __restrict__ X, const float* __restrict__ W,
               const float* __restrict__ U, const float* __restrict__ B,
               const float* __restrict__ LW, const float* __restrict__ LB,
               float* __restrict__ OUT, unsigned short* __restrict__ Zbuf,
               int* __restrict__ ready, int* __restrict__ done) {
  __shared__ __align__(16) short Hb[2][16 * HSTR];   // rows 4..15 stay zero
  __shared__ float Ys[RPG * HS];

  const int tid  = threadIdx.x;
  const int lane = tid & 63;
  const int w    = tid >> 6;
  const int lrow = lane & 15;
  const int lg   = lane >> 4;
  const int blk  = blockIdx.x;

  if (blk >= GROUPS) {
    // ===================== producer: one block per group ===================
    const int g = blk - GROUPS;
    s16x8 bfrW[4][2];
    float biasg[4];
#pragma unroll
    for (int n = 0; n < 4; ++n) {
      const int p = n * HS + w * 16 + lrow;
#pragma unroll
      for (int kt = 0; kt < 2; ++kt)
#pragma unroll
        for (int j = 0; j < 8; ++j)
          bfrW[n][kt][j] = (short)f2bf(W[(kt * 32 + lg * 8 + j) * NG + p]);
      biasg[n] = B[p];
    }
    // A-tile: row = lrow -> (t-local = lrow>>2, batch row = lrow&3)
    const float* xb = X + ((long)(g * RPG + (lrow & 3)) * T_STEPS + (lrow >> 2)) * IN_DIM + lg * 8;

#pragma unroll 1
    for (int c = 0; c < NCHK; ++c) {
      if (c >= RING) {                       // ring guard
        if (tid < 64) wait_ge(&done[g], c - RING + 1);
        __syncthreads();
      }
#pragma unroll 1
      for (int mt = 0; mt < 8; ++mt) {
        const float* xp = xb + (long)(c * CHK + mt * 4) * IN_DIM;
        const f32x4 x0 = *(const f32x4*)(xp);
        const f32x4 x1 = *(const f32x4*)(xp + 4);
        const f32x4 x2 = *(const f32x4*)(xp + 32);
        const f32x4 x3 = *(const f32x4*)(xp + 36);
        s16x8 a0, a1;
#pragma unroll
        for (int j = 0; j < 4; ++j) {
          a0[j] = (short)f2bf(x0[j]); a0[4 + j] = (short)f2bf(x1[j]);
          a1[j] = (short)f2bf(x2[j]); a1[4 + j] = (short)f2bf(x3[j]);
        }
        f32x4 ac[4];
#pragma unroll
        for (int n = 0; n < 4; ++n) {
          ac[n][0] = biasg[n]; ac[n][1] = biasg[n];
          ac[n][2] = biasg[n]; ac[n][3] = biasg[n];
        }
#pragma unroll
        for (int n = 0; n < 4; ++n)
          ac[n] = __builtin_amdgcn_mfma_f32_16x16x32_bf16(a0, bfrW[n][0], ac[n], 0, 0, 0);
#pragma unroll
        for (int n = 0; n < 4; ++n)
          ac[n] = __builtin_amdgcn_mfma_f32_16x16x32_bf16(a1, bfrW[n][1], ac[n], 0, 0, 0);
        // D row d = 4lg+rr -> t = c*32 + mt*4 + lg, batch row rr
        s16x8 zl, zh;
#pragma unroll
        for (int n = 0; n < 4; ++n) {
          zl[n] = (short)f2bf(ac[n][0]); zl[4 + n] = (short)f2bf(ac[n][1]);
          zh[n] = (short)f2bf(ac[n][2]); zh[4 + n] = (short)f2bf(ac[n][3]);
        }
        const int tsl = (c % RING) * CHK + mt * 4 + lg;   // ring t-slot
        unsigned short* dst = Zbuf + ((((long)tsl * GROUPS + g) * 128) + w * 16 + lrow) * 16;
        *(s16x8*)dst       = zl;
        *(s16x8*)(dst + 8) = zh;
      }
      __threadfence();
      __syncthreads();
      if (tid == 0)
        __hip_atomic_store(&ready[c * GROUPS + g], 1, __ATOMIC_RELEASE, __HIP_MEMORY_SCOPE_AGENT);
    }
    return;
  }

  // =========================== scan: 4 rows/block ==========================
  const int g = blk;
  s16x8 bfrU[4][4];
#pragma unroll
  for (int n = 0; n < 4; ++n) {
    const int p = n * HS + w * 16 + lrow;
#pragma unroll
    for (int kt = 0; kt < 4; ++kt)
#pragma unroll
      for (int j = 0; j < 8; ++j)
        bfrU[n][kt][j] = (short)f2bf(U[(kt * 32 + lg * 8 + j) * NG + p]);
  }
  for (int i = tid; i < 2 * 16 * HSTR; i += NTHR) ((short*)Hb)[i] = 0;  // h(0)=0

  if (tid < 64) wait_ge(&ready[g], 1);      // chunk 0 ready (acquire -> inv)
  __syncthreads();

  const int sl = w * 16 + lrow;             // this lane's Z cell / gate col
  const int baddr = (lane & 31) << 2;       // bpermute byte index
  auto zaddr = [&](int ts) -> const unsigned short* {
    const int tsl = ((ts >> 5) % RING) * CHK + (ts & 31);
    return Zbuf + ((((long)tsl * GROUPS + g) * 128) + sl) * 16;
  };
  const unsigned short* pz = zaddr(0);
  s16x8 za0 = *(const s16x8*)pz, za1 = *(const s16x8*)(pz + 8);
  pz = zaddr(1);
  s16x8 zb0 = *(const s16x8*)pz, zb1 = *(const s16x8*)(pz + 8);

  s16x8 afr[4];
  const s16x8 zer = {0, 0, 0, 0, 0, 0, 0, 0};
#pragma unroll
  for (int kt = 0; kt < 4; ++kt) afr[kt] = zer;
  float creg = 0.f;

  auto step = [&](int t, s16x8& z0, s16x8& z1) {
    f32x4 acc[4];
#pragma unroll
    for (int n = 0; n < 4; ++n) {
      acc[n][0] = bf2f((unsigned short)z0[n]);
      acc[n][1] = bf2f((unsigned short)z0[4 + n]);
      acc[n][2] = bf2f((unsigned short)z1[n]);
      acc[n][3] = bf2f((unsigned short)z1[4 + n]);
    }
    {   // prefetch Z(t+2) into this slot
      const int tn = (t + 2 < T_STEPS) ? t + 2 : T_STEPS - 1;
      const unsigned short* src = zaddr(tn);
      z0 = *(const s16x8*)src;
      z1 = *(const s16x8*)(src + 8);
    }

    __builtin_amdgcn_s_setprio(1);
#pragma unroll
    for (int kt = 0; kt < 4; ++kt)
      acc[0] = __builtin_amdgcn_mfma_f32_16x16x32_bf16(afr[kt], bfrU[0][kt], acc[0], 0, 0, 0);
#pragma unroll
    for (int kt = 0; kt < 4; ++kt)
      acc[2] = __builtin_amdgcn_mfma_f32_16x16x32_bf16(afr[kt], bfrU[2][kt], acc[2], 0, 0, 0);
#pragma unroll
    for (int kt = 0; kt < 4; ++kt)
      acc[1] = __builtin_amdgcn_mfma_f32_16x16x32_bf16(afr[kt], bfrU[1][kt], acc[1], 0, 0, 0);
#pragma unroll
    for (int kt = 0; kt < 4; ++kt)
      acc[3] = __builtin_amdgcn_mfma_f32_16x16x32_bf16(afr[kt], bfrU[3][kt], acc[3], 0, 0, 0);
    __builtin_amdgcn_s_setprio(0);

    // redistribute: lane (lg,lrow) <- acc[n][lg] of lane (0,lrow).
    // Phase A (valid xor16 swizzles, 32-lane confined): lanes lg=0 hold
    // rows {0,2} in {acc0,acc2}; lanes lg=1 pull rows {1,3} via xor16.
    // Phase B: full-wave ds_bpermute delivers rows 2/3 to lanes 32..63.
    float v[4];
#pragma unroll
    for (int n = 0; n < 4; ++n) {
      const float t1 = __int_as_float(
          __builtin_amdgcn_ds_swizzle(__float_as_int(acc[n][1]), 0x401F));  // xor16
      const float t3 = __int_as_float(
          __builtin_amdgcn_ds_swizzle(__float_as_int(acc[n][3]), 0x401F));  // xor16
      const float lo = (lane & 16) ? t1 : acc[n][0];   // rows 0 / 1
      const float hi = (lane & 16) ? t3 : acc[n][2];   // rows 2 / 3
      const float hb = __int_as_float(
          __builtin_amdgcn_ds_bpermute(baddr, __float_as_int(hi)));
      v[n] = (lane & 32) ? hb : lo;
    }
    const float iv = sigm(v[0]), fv = sigm(v[1]);
    const float gv = tanhfast(v[2]), ov = sigm(v[3]);
    creg = fv * creg + iv * gv;
    const float hv = ov * tanhfast(creg);

    if (t < T_STEPS - 1) {
      Hb[(t + 1) & 1][lg * HSTR + sl] = (short)f2bf(hv);
    } else {
      const int row = g * RPG + lg;
      OUT[512 + row * HS + sl]   = hv;      // h_t
      OUT[66048 + row * HS + sl] = creg;    // c_t
      Ys[lg * HS + sl] = LW[sl] * hv;       // y partials
    }

    // acquire next chunk mid-chunk (producer is far ahead after startup)
    if ((t & 31) == 16 && ((t >> 5) + 1) < NCHK) {
      if (tid < 64) wait_ge(&ready[((t >> 5) + 1) * GROUPS + g], 1);
    }
    __syncthreads();
    // chunk fully consumed -> free ring slot
    if ((t & 31) == 31 && tid == 0)
      __hip_atomic_store(&done[g], (t >> 5) + 1, __ATOMIC_RELEASE, __HIP_MEMORY_SCOPE_AGENT);

    if (t < T_STEPS - 1) {
      const short* hp = &Hb[(t + 1) & 1][lrow * HSTR];
      afr[0] = *(const s16x8*)&hp[lg * 8];
      afr[1] = *(const s16x8*)&hp[32 + lg * 8];
      afr[2] = *(const s16x8*)&hp[64 + lg * 8];
      afr[3] = *(const s16x8*)&hp[96 + lg * 8];
    }
  };

#pragma unroll 1
  for (int t = 0; t < T_STEPS; t += 2) {
    step(t, za0, za1);
    step(t + 1, zb0, zb1);
  }

  __syncthreads();
  // y = h @ linear_w.T + b
  if (w < RPG) {
    float v = Ys[w * HS + lane] + Ys[w * HS + 64 + lane];
#pragma unroll
    for (int off = 32; off > 0; off >>= 1) v += __shfl_down(v, off);
    if (lane == 0) OUT[g * RPG + w] = v + LB[0];
  }
}

// ---------------------------------------------------------------------------
// Fallback (ws too small): R5 fused kernel, 256 blocks x 2 rows.
// ---------------------------------------------------------------------------
#define ROWS 2
#define CH 64
#define NCH (T_STEPS / CH)

__global__ __launch_bounds__(NTHR, 1)
void lstm_fused(const float* __restrict__ X, const float* __restrict__ W,
                const float* __restrict__ U, const float* __restrict__ B,
                const float* __restrict__ LW, const float* __restrict__ LB,
                float* __restrict__ OUT) {
  __shared__ __align__(16) short Zc[CH * 128 * 8];
  __shared__ __align__(16) short Hb[2][ROWS * 144];
  __shared__ float Ys[256];
  __shared__ float Ps[8];

  const int tid  = threadIdx.x;
  const int lane = tid & 63;
  const int w    = tid >> 6;
  const int blk  = blockIdx.x;
  const int lrow = lane & 15;
  const int lg   = lane >> 4;
  const int col8 = (w * 16 + lrow) * 8;

  s16x8 bfrU[4][4];
  s16x8 bfrW[4][2];
  float biasg[4];
#pragma unroll
  for (int n = 0; n < 4; ++n) {
    const int p = n * HS + w * 16 + lrow;
#pragma unroll
    for (int kt = 0; kt < 4; ++kt)
#pragma unroll
      for (int j = 0; j < 8; ++j)
        bfrU[n][kt][j] = (short)f2bf(U[(kt * 32 + (lg << 3) + j) * NG + p]);
#pragma unroll
    for (int kt = 0; kt < 2; ++kt)
#pragma unroll
      for (int j = 0; j < 8; ++j)
        bfrW[n][kt][j] = (short)f2bf(W[(kt * 32 + (lg << 3) + j) * NG + p]);
    biasg[n] = B[p];
  }

  const float* xbA = X + ((long)(blk * ROWS + (lrow & 1)) * T_STEPS + (lrow >> 1)) * IN_DIM + (lg << 3);
  f32x4 qp0 = *(const f32x4*)(xbA);
  f32x4 qp1 = *(const f32x4*)(xbA + 4);
  f32x4 qp2 = *(const f32x4*)(xbA + 32);
  f32x4 qp3 = *(const f32x4*)(xbA + 36);

  s16x8 afr[4];
  const s16x8 zer = {0, 0, 0, 0, 0, 0, 0, 0};
#pragma unroll
  for (int kt = 0; kt < 4; ++kt) afr[kt] = zer;
  float creg = 0.f, hreg = 0.f;

#pragma unroll 1
  for (int c = 0; c < NCH; ++c) {
    {
      const float* xc = xbA + (long)c * CH * IN_DIM;
      f32x4 q0 = qp0, q1 = qp1, q2 = qp2, q3 = qp3;
#pragma unroll
      for (int mt = 0; mt < 8; ++mt) {
        f32x4 n0, n1, n2, n3;
        if (mt < 7) {
          const float* p = xc + (mt + 1) * 8 * IN_DIM;
          n0 = *(const f32x4*)(p);      n1 = *(const f32x4*)(p + 4);
          n2 = *(const f32x4*)(p + 32); n3 = *(const f32x4*)(p + 36);
        }
        s16x8 a0, a1;
#pragma unroll
        for (int j = 0; j < 4; ++j) {
          a0[j] = (short)f2bf(q0[j]); a0[4 + j] = (short)f2bf(q1[j]);
          a1[j] = (short)f2bf(q2[j]); a1[4 + j] = (short)f2bf(q3[j]);
        }
        f32x4 ac[4];
#pragma unroll
        for (int n = 0; n < 4; ++n) {
          ac[n][0] = biasg[n]; ac[n][1] = biasg[n];
          ac[n][2] = biasg[n]; ac[n][3] = biasg[n];
        }
#pragma unroll
        for (int n = 0; n < 4; ++n)
          ac[n] = __builtin_amdgcn_mfma_f32_16x16x32_bf16(a0, bfrW[n][0], ac[n], 0, 0, 0);
#pragma unroll
        for (int n = 0; n < 4; ++n)
          ac[n] = __builtin_amdgcn_mfma_f32_16x16x32_bf16(a1, bfrW[n][1], ac[n], 0, 0, 0);
        s16x8 z0, z1;
#pragma unroll
        for (int n = 0; n < 4; ++n) {
          z0[n] = (short)f2bf(ac[n][0]); z0[4 + n] = (short)f2bf(ac[n][1]);
          z1[n] = (short)f2bf(ac[n][2]); z1[4 + n] = (short)f2bf(ac[n][3]);
        }
        const int tl0 = mt * 8 + 2 * lg;
        *(s16x8*)&Zc[tl0 * 1024 + col8]       = z0;
        *(s16x8*)&Zc[(tl0 + 1) * 1024 + col8] = z1;
        q0 = n0; q1 = n1; q2 = n2; q3 = n3;
      }
      const float* pn = xbA + (long)((c + 1 < NCH) ? c + 1 : c) * CH * IN_DIM;
      qp0 = *(const f32x4*)(pn);      qp1 = *(const f32x4*)(pn + 4);
      qp2 = *(const f32x4*)(pn + 32); qp3 = *(const f32x4*)(pn + 36);
    }
    __syncthreads();

#pragma unroll 1
    for (int tl = 0; tl < CH; ++tl) {
      const int t = (c << 6) + tl;
      const s16x8 zc = *(const s16x8*)&Zc[tl * 1024 + col8];
      f32x4 acc[4];
#pragma unroll
      for (int n = 0; n < 4; ++n) {
        acc[n][0] = bf2f((unsigned short)zc[n]);
        acc[n][1] = bf2f((unsigned short)zc[4 + n]);
        acc[n][2] = 0.f; acc[n][3] = 0.f;
      }
      __builtin_amdgcn_s_setprio(1);
#pragma unroll
      for (int kt = 0; kt < 4; ++kt)
        acc[0] = __builtin_amdgcn_mfma_f32_16x16x32_bf16(afr[kt], bfrU[0][kt], acc[0], 0, 0, 0);
#pragma unroll
      for (int kt = 0; kt < 4; ++kt)
        acc[2] = __builtin_amdgcn_mfma_f32_16x16x32_bf16(afr[kt], bfrU[2][kt], acc[2], 0, 0, 0);
#pragma unroll
      for (int kt = 0; kt < 4; ++kt)
        acc[1] = __builtin_amdgcn_mfma_f32_16x16x32_bf16(afr[kt], bfrU[1][kt], acc[1], 0, 0, 0);
#pragma unroll
      for (int kt = 0; kt < 4; ++kt)
        acc[3] = __builtin_amdgcn_mfma_f32_16x16x32_bf16(afr[kt], bfrU[3][kt], acc[3], 0, 0, 0);
      __builtin_amdgcn_s_setprio(0);

      const float s0 = __int_as_float(
          __builtin_amdgcn_ds_swizzle(__float_as_int(acc[0][1]), 0x401F));
      const float s2 = __int_as_float(
          __builtin_amdgcn_ds_swizzle(__float_as_int(acc[2][1]), 0x401F));
      const float v0 = (lane & 16) ? s0 : acc[0][0];
      const float v2 = (lane & 16) ? s2 : acc[2][0];
      const float iv = sigm(v0), gv = tanhfast(v2);
      const float pg = iv * gv;
      const float s1 = __int_as_float(
          __builtin_amdgcn_ds_swizzle(__float_as_int(acc[1][1]), 0x401F));
      const float s3 = __int_as_float(
          __builtin_amdgcn_ds_swizzle(__float_as_int(acc[3][1]), 0x401F));
      const float v1 = (lane & 16) ? s1 : acc[1][0];
      const float v3 = (lane & 16) ? s3 : acc[3][0];
      const float fv = sigm(v1), ov = sigm(v3);
      creg = fv * creg + pg;
      hreg = ov * tanhfast(creg);

      if (lane < 32) {
        const int colc = w * 16 + lrow;
        const int r    = lg & 1;
        if (t < T_STEPS - 1) {
          Hb[(t + 1) & 1][r * 144 + colc] = (short)f2bf(hreg);
        } else {
          const int row = blk * ROWS + r;
          OUT[512 + row * HS + colc]   = hreg;
          OUT[66048 + row * HS + colc] = creg;
          Ys[r * HS + colc] = LW[colc] * hreg;
        }
      }
      __syncthreads();

      if (t < T_STEPS - 1 && lrow < ROWS) {
        const short* hb = &Hb[(t + 1) & 1][lrow * 144];
        afr[0] = *(const s16x8*)&hb[(lg << 3)];
        afr[1] = *(const s16x8*)&hb[32 + (lg << 3)];
        afr[2] = *(const s16x8*)&hb[64 + (lg << 3)];
        afr[3] = *(const s16x8*)&hb[96 + (lg << 3)];
      }
    }
  }

  if (tid < 8) {
    const int r = tid >> 2, seg = tid & 3;
    float s = 0.f;
#pragma unroll 8
    for (int j = 0; j < 32; ++j) s += Ys[r * 128 + seg * 32 + j];
    Ps[tid] = s;
  }
  __syncthreads();
  if (tid < ROWS) {
    OUT[blk * ROWS + tid] = LB[0] + Ps[tid * 4] + Ps[tid * 4 + 1]
                                  + Ps[tid * 4 + 2] + Ps[tid * 4 + 3];
  }
}

extern "C" void kernel_launch(void* const* d_in, const int* in_sizes, int n_in,
                              void* d_out, int out_size, void* d_ws, size_t ws_size,
                              hipStream_t stream) {
  const float* X  = (const float*)d_in[0];
  const float* W  = (const float*)d_in[1];
  const float* U  = (const float*)d_in[2];
  const float* B  = (const float*)d_in[3];
  const float* LW = (const float*)d_in[4];
  const float* LB = (const float*)d_in[5];
  const size_t ZBYTES = (size_t)RING * CHK * GROUPS * 128 * 16 * 2;  // 192 MiB
  const size_t FBYTES = (size_t)(NUNITS + GROUPS) * 4;               // 33 KB
  if (ws_size >= ZBYTES + FBYTES) {
    unsigned short* Zbuf = (unsigned short*)d_ws;
    int* flg = (int*)((char*)d_ws + ZBYTES);
    hipMemsetAsync(flg, 0, FBYTES, stream);
    lstm_mega<<<dim3(GROUPS + PRODS), dim3(NTHR), 0, stream>>>(
        X, W, U, B, LW, LB, (float*)d_out, Zbuf, flg, flg + NUNITS);
  } else {
    lstm_fused<<<dim3(256), dim3(NTHR), 0, stream>>>(X, W, U, B, LW, LB, (float*)d_out);
  }
}

// Round 13
// 1332.474 us; speedup vs baseline: 3.9159x; 3.9159x over previous
//
#include <hip/hip_runtime.h>

// LSTM BS=512, T=2048, IN=64, HS=128.  Single fused persistent kernel.
// 256 blocks x 2 batch rows, 8 waves. Scan body = R5's (best measured).
// Chunk GEMM (Z = x@W + bias, CH=32 steps) reads x from an LDS tile staged
// during the PREVIOUS chunk's scan steps (T14 async split: loads issued at
// GEMM-end, ds_write at scan step 4) -> the GEMM phase has zero global ops.
// Xl uses an XOR swizzle to kill the 16-way lg bank alias.
// R13 fix vs R12: stage_load timestep index was double-counting w*8 (OOB).

#define T_STEPS 2048
#define IN_DIM 64
#define HS 128
#define NG 512
#define ROWS 2
#define NBLK 256
#define NTHR 512
#define HSTR 144
#define CH 32
#define NCH (T_STEPS / CH)

typedef float f32x4 __attribute__((ext_vector_type(4)));
typedef short s16x8 __attribute__((ext_vector_type(8)));

__device__ __forceinline__ unsigned short f2bf(float f) {
  unsigned u = __float_as_uint(f);
  return (unsigned short)((u + 0x7fffu + ((u >> 16) & 1u)) >> 16);  // RNE
}
__device__ __forceinline__ float bf2f(unsigned short s) {
  return __int_as_float(((int)s) << 16);
}
__device__ __forceinline__ float rcpf(float x) { return __builtin_amdgcn_rcpf(x); }
__device__ __forceinline__ float sigm(float x) { return rcpf(1.0f + __expf(-x)); }
__device__ __forceinline__ float tanhfast(float x) {
  return 1.0f - 2.0f * rcpf(__expf(2.0f * x) + 1.0f);  // exact at +-inf
}
// Xl float-index swizzle: XOR t' (bits 7..9) into the 8-float granule bits
__device__ __forceinline__ int xswz(int f) { return f ^ (((f >> 7) & 7) << 3); }

__global__ __launch_bounds__(NTHR, 1)
void lstm_fused(const float* __restrict__ X, const float* __restrict__ W,
                const float* __restrict__ U, const float* __restrict__ B,
                const float* __restrict__ LW, const float* __restrict__ LB,
                float* __restrict__ OUT) {
  // Zc cell (tl, col): 8 shorts = [r0:n0..n3 | r1:n0..n3]
  __shared__ __align__(16) short Zc[CH * 128 * 8];     // 64 KB
  __shared__ __align__(16) float Xl[4096];             // 16 KB x-tile (swizzled)
  __shared__ __align__(16) short Hb[2][ROWS * HSTR];   // h double buffer
  __shared__ float Ys[256];
  __shared__ float Ps[8];

  const int tid  = threadIdx.x;
  const int lane = tid & 63;
  const int w    = tid >> 6;
  const int blk  = blockIdx.x;
  const int lrow = lane & 15;
  const int lg   = lane >> 4;
  const int col8 = (w * 16 + lrow) * 8;   // Zc column offset (shorts)

  // ---- persistent weight fragments: wave w owns col p = n*128 + 16w + lrow
  s16x8 bfrU[4][4];   // K=128 (U)
  s16x8 bfrW[4][2];   // K=64  (W)
  float biasg[4];
#pragma unroll
  for (int n = 0; n < 4; ++n) {
    const int p = n * HS + w * 16 + lrow;
#pragma unroll
    for (int kt = 0; kt < 4; ++kt)
#pragma unroll
      for (int j = 0; j < 8; ++j)
        bfrU[n][kt][j] = (short)f2bf(U[(kt * 32 + (lg << 3) + j) * NG + p]);
#pragma unroll
    for (int kt = 0; kt < 2; ++kt)
#pragma unroll
      for (int j = 0; j < 8; ++j)
        bfrW[n][kt][j] = (short)f2bf(W[(kt * 32 + (lg << 3) + j) * NG + p]);
    biasg[n] = B[p];
  }

  // ---- x staging (T14 split): waves 0..3 own m-tile w of the chunk ----
  // Xl layout (pre-swizzle): f = t_local*128 + row*64 + k  (t_local 0..31)
  f32x4 sx0, sx1, sx2, sx3;
  auto stage_load = [&](int cc) {   // issue 4 global f32x4 loads (chunk cc)
    if (w < 4) {
#pragma unroll
      for (int q = 0; q < 4; ++q) {
        const int f   = w * 1024 + q * 256 + lane * 4;
        const int tlc = f >> 7;          // t-local 0..31 (includes w*8)
        const int row = (f >> 6) & 1;
        const int k   = f & 63;
        const f32x4 v = *(const f32x4*)(
            X + ((long)(blk * ROWS + row) * T_STEPS + (long)cc * CH + tlc) * IN_DIM + k);
        if (q == 0) sx0 = v; else if (q == 1) sx1 = v;
        else if (q == 2) sx2 = v; else sx3 = v;
      }
    }
  };
  auto stage_write = [&]() {        // commit to LDS (swizzled)
    if (w < 4) {
#pragma unroll
      for (int q = 0; q < 4; ++q) {
        const int f = w * 1024 + q * 256 + lane * 4;
        const f32x4 v = (q == 0) ? sx0 : (q == 1) ? sx1 : (q == 2) ? sx2 : sx3;
        *(f32x4*)&Xl[xswz(f)] = v;
      }
    }
  };

  // prologue: stage chunk 0
  stage_load(0);
  stage_write();

  s16x8 afr[4];
  const s16x8 zer = {0, 0, 0, 0, 0, 0, 0, 0};
#pragma unroll
  for (int kt = 0; kt < 4; ++kt) afr[kt] = zer;  // h(0) = 0

  float creg = 0.f, hreg = 0.f;
  __syncthreads();

#pragma unroll 1
  for (int c = 0; c < NCH; ++c) {
    // ============ chunk GEMM: Zc = x@W + bias, x from LDS (no global) ======
#pragma unroll
    for (int mt = 0; mt < 4; ++mt) {
      const int fb = mt * 1024 + (lrow >> 1) * 128 + (lrow & 1) * 64;
      const int f0 = xswz(fb + 8 * lg);        // kt=0 (k = 8lg..8lg+7)
      const int f1 = xswz(fb + 32 + 8 * lg);   // kt=1 (k = 32+8lg..)
      const f32x4 x0 = *(const f32x4*)&Xl[f0];
      const f32x4 x1 = *(const f32x4*)&Xl[f0 + 4];
      const f32x4 x2 = *(const f32x4*)&Xl[f1];
      const f32x4 x3 = *(const f32x4*)&Xl[f1 + 4];
      s16x8 a0, a1;
#pragma unroll
      for (int j = 0; j < 4; ++j) {
        a0[j] = (short)f2bf(x0[j]); a0[4 + j] = (short)f2bf(x1[j]);
        a1[j] = (short)f2bf(x2[j]); a1[4 + j] = (short)f2bf(x3[j]);
      }
      f32x4 ac[4];
#pragma unroll
      for (int n = 0; n < 4; ++n) {
        ac[n][0] = biasg[n]; ac[n][1] = biasg[n];
        ac[n][2] = biasg[n]; ac[n][3] = biasg[n];
      }
#pragma unroll
      for (int n = 0; n < 4; ++n)
        ac[n] = __builtin_amdgcn_mfma_f32_16x16x32_bf16(a0, bfrW[n][0], ac[n], 0, 0, 0);
#pragma unroll
      for (int n = 0; n < 4; ++n)
        ac[n] = __builtin_amdgcn_mfma_f32_16x16x32_bf16(a1, bfrW[n][1], ac[n], 0, 0, 0);
      // D row d=4lg+rr -> m-row 16mt+d -> (tl = 8mt+2lg+(rr>>1), r = rr&1)
      s16x8 z0, z1;
#pragma unroll
      for (int n = 0; n < 4; ++n) {
        z0[n] = (short)f2bf(ac[n][0]); z0[4 + n] = (short)f2bf(ac[n][1]);
        z1[n] = (short)f2bf(ac[n][2]); z1[4 + n] = (short)f2bf(ac[n][3]);
      }
      const int tl0 = mt * 8 + 2 * lg;
      *(s16x8*)&Zc[tl0 * 1024 + col8]       = z0;
      *(s16x8*)&Zc[(tl0 + 1) * 1024 + col8] = z1;
    }
    __syncthreads();                     // Zc ready; Xl consumed
    stage_load((c + 1 < NCH) ? c + 1 : c);   // issue next chunk's x loads

    // ============ 32 scan steps (R5 body) ==================================
#pragma unroll 1
    for (int tl = 0; tl < CH; ++tl) {
      const int t = c * CH + tl;
      const s16x8 zc = *(const s16x8*)&Zc[tl * 1024 + col8];
      f32x4 acc[4];
#pragma unroll
      for (int n = 0; n < 4; ++n) {
        acc[n][0] = bf2f((unsigned short)zc[n]);
        acc[n][1] = bf2f((unsigned short)zc[4 + n]);
        acc[n][2] = 0.f; acc[n][3] = 0.f;
      }
      __builtin_amdgcn_s_setprio(1);
#pragma unroll
      for (int kt = 0; kt < 4; ++kt)
        acc[0] = __builtin_amdgcn_mfma_f32_16x16x32_bf16(afr[kt], bfrU[0][kt], acc[0], 0, 0, 0);
#pragma unroll
      for (int kt = 0; kt < 4; ++kt)
        acc[2] = __builtin_amdgcn_mfma_f32_16x16x32_bf16(afr[kt], bfrU[2][kt], acc[2], 0, 0, 0);
#pragma unroll
      for (int kt = 0; kt < 4; ++kt)
        acc[1] = __builtin_amdgcn_mfma_f32_16x16x32_bf16(afr[kt], bfrU[1][kt], acc[1], 0, 0, 0);
#pragma unroll
      for (int kt = 0; kt < 4; ++kt)
        acc[3] = __builtin_amdgcn_mfma_f32_16x16x32_bf16(afr[kt], bfrU[3][kt], acc[3], 0, 0, 0);
      __builtin_amdgcn_s_setprio(0);

      if (tl == 4) stage_write();        // x arrived long ago; Xl free

      // i,g first (their accs finish first), f,o while i*g computes
      const float s0 = __int_as_float(
          __builtin_amdgcn_ds_swizzle(__float_as_int(acc[0][1]), 0x401F));
      const float s2 = __int_as_float(
          __builtin_amdgcn_ds_swizzle(__float_as_int(acc[2][1]), 0x401F));
      const float v0 = (lane & 16) ? s0 : acc[0][0];
      const float v2 = (lane & 16) ? s2 : acc[2][0];
      const float iv = sigm(v0), gv = tanhfast(v2);
      const float pg = iv * gv;
      const float s1 = __int_as_float(
          __builtin_amdgcn_ds_swizzle(__float_as_int(acc[1][1]), 0x401F));
      const float s3 = __int_as_float(
          __builtin_amdgcn_ds_swizzle(__float_as_int(acc[3][1]), 0x401F));
      const float v1 = (lane & 16) ? s1 : acc[1][0];
      const float v3 = (lane & 16) ? s3 : acc[3][0];
      const float fv = sigm(v1), ov = sigm(v3);
      creg = fv * creg + pg;
      hreg = ov * tanhfast(creg);

      if (lane < 32) {
        const int colc = w * 16 + lrow;
        const int r    = lg & 1;
        if (t < T_STEPS - 1) {
          Hb[(t + 1) & 1][r * HSTR + colc] = (short)f2bf(hreg);
        } else {
          const int row = blk * ROWS + r;
          OUT[512 + row * HS + colc]   = hreg;   // h_t
          OUT[66048 + row * HS + colc] = creg;   // c_t
          Ys[r * HS + colc] = LW[colc] * hreg;   // y partials
        }
      }
      __syncthreads();

      if (t < T_STEPS - 1 && lrow < ROWS) {      // h fragments for step t+1
        const short* hb = &Hb[(t + 1) & 1][lrow * HSTR];
        afr[0] = *(const s16x8*)&hb[(lg << 3)];
        afr[1] = *(const s16x8*)&hb[32 + (lg << 3)];
        afr[2] = *(const s16x8*)&hb[64 + (lg << 3)];
        afr[3] = *(const s16x8*)&hb[96 + (lg << 3)];
      }
    }
  }

  // ---- y = h @ linear_w.T + b ----
  if (tid < 8) {
    const int r = tid >> 2, seg = tid & 3;
    float s = 0.f;
#pragma unroll 8
    for (int j = 0; j < 32; ++j) s += Ys[r * 128 + seg * 32 + j];
    Ps[tid] = s;
  }
  __syncthreads();
  if (tid < ROWS) {
    OUT[blk * ROWS + tid] = LB[0] + Ps[tid * 4] + Ps[tid * 4 + 1]
                                  + Ps[tid * 4 + 2] + Ps[tid * 4 + 3];
  }
}

extern "C" void kernel_launch(void* const* d_in, const int* in_sizes, int n_in,
                              void* d_out, int out_size, void* d_ws, size_t ws_size,
                              hipStream_t stream) {
  const float* X  = (const float*)d_in[0];
  const float* W  = (const float*)d_in[1];
  const float* U  = (const float*)d_in[2];
  const float* B  = (const float*)d_in[3];
  const float* LW = (const float*)d_in[4];
  const float* LB = (const float*)d_in[5];
  lstm_fused<<<dim3(NBLK), dim3(NTHR), 0, stream>>>(X, W, U, B, LW, LB, (float*)d_out);
}